// Round 12
// baseline (666.854 us; speedup 1.0000x reference)
//
#include <hip/hip_runtime.h>

#define NUM_USERS 100000
#define NUM_ITEMS 50000
#define N_NODES   150000   // NUM_USERS + NUM_ITEMS
#define EMBED_DIM 64
#define NUM_EDGES 4000000

#define N_USER4  (NUM_USERS * EMBED_DIM / 4)   // 1,600,000
#define N_TOT4   (N_NODES  * EMBED_DIM / 4)    // 2,400,000

// bucket sort parameters: 293 buckets x 512 rows (R11: line-sized tmp runs)
#define BROWS_SHIFT 9
#define BROWS       (1 << BROWS_SHIFT)                    // 512
#define NB          ((N_NODES + BROWS - 1) / BROWS)       // 293
#define BIN_TILE    4096                                  // edges per tile
#define NTILES      ((NUM_EDGES + BIN_TILE - 1) / BIN_TILE)  // 977
#define CAP         16384  // tmp slots per bucket (mean 13653, sigma 117)

#define CURPAD 16          // ints per cursor: one 64B line each (R8 lesson)
#define CHUNKS 4           // finalize blocks per bucket (R12: 1172 blocks)
#define NSB 586            // row-scan blocks: 586 x 256 covers 150K rows
#define RPW 4              // rows per wave in spmm

// bf16 helpers: store with round-to-nearest-even, load with shift (exact)
__device__ __forceinline__ unsigned short f2bf(float f) {
    unsigned int u = __float_as_uint(f);
    u = (u + 0x7fffu + ((u >> 16) & 1u)) >> 16;
    return (unsigned short)u;
}
__device__ __forceinline__ float bf2f(unsigned short b) {
    return __uint_as_float((unsigned int)b << 16);
}

// ---------------------------------------------------------------------------
// init: cur(bf16) = emb; zero padded bucket cursors + per-row counters.
// ---------------------------------------------------------------------------
__global__ void init_kernel(const float4* __restrict__ ue,
                            const float4* __restrict__ ie,
                            ushort4* __restrict__ cur_bf,
                            int* __restrict__ gcur,
                            int* __restrict__ rcnt) {
    int i = blockIdx.x * blockDim.x + threadIdx.x;
    if (i < NB * CURPAD) gcur[i] = 0;
    if (i < N_NODES) rcnt[i] = 0;
    if (i >= N_TOT4) return;
    float4 v = (i < N_USER4) ? ue[i] : ie[i - N_USER4];
    ushort4 b;
    b.x = f2bf(v.x); b.y = f2bf(v.y); b.z = f2bf(v.z); b.w = f2bf(v.w);
    cur_bf[i] = b;
}

// ---------------------------------------------------------------------------
// Fused build pass 1: rank + place per 4096-edge tile (R11 structure) PLUS a
// fire-and-forget per-row degree count (R12): 4M atomics over 9375 lines
// (~427 ops/line — the benign regime; no return wait).
// tmp entry packs (rl<<18 | col, val): col<2^18, rl<2^9 (bits 18..26).
// pkreg packs (b<<21 | rl<<12 | rk): b<2^9, rl<2^9, rk<2^12 -> positive.
// ---------------------------------------------------------------------------
__global__ void bin_write_fused(const int*   __restrict__ row,
                                const int*   __restrict__ col,
                                const float* __restrict__ val,
                                int*  __restrict__ gcur,   // NB padded cursors
                                int*  __restrict__ rcnt,   // per-row degrees
                                int2* __restrict__ tmp) {
    __shared__ int2 sbuf[BIN_TILE];                 // 32 KB
    __shared__ unsigned short sbk[BIN_TILE];        // 8 KB
    __shared__ int h[NB];                           // counts, then global base
    __shared__ int lbase[NB];
    __shared__ int ps[256];
    int tid = threadIdx.x;
    long e0 = (long)blockIdx.x * BIN_TILE;

    for (int i = tid; i < NB; i += 256) h[i] = 0;
    __syncthreads();

    // rank phase (+ global per-row degree count, fire-and-forget)
    int pkreg[BIN_TILE / 256];
    #pragma unroll
    for (int k = 0; k < BIN_TILE / 256; ++k) {
        long e = e0 + tid + k * 256;
        pkreg[k] = -1;
        if (e < NUM_EDGES) {
            int r  = row[e];
            atomicAdd(&rcnt[r], 1);
            int b  = r >> BROWS_SHIFT;
            int rl = r & (BROWS - 1);
            int rk = atomicAdd(&h[b], 1);
            pkreg[k] = (b << 21) | (rl << 12) | rk;
        }
    }
    __syncthreads();

    // exclusive scan of h[NB] -> lbase (2 bins/thread, 512 >= 293);
    // then claim this tile's global base per bucket: h[i] = old gcur
    int a[2]; int s = 0;
    #pragma unroll
    for (int j = 0; j < 2; ++j) {
        int i = tid * 2 + j;
        a[j] = (i < NB) ? h[i] : 0;
        s += a[j];
    }
    ps[tid] = s;
    __syncthreads();
    for (int off = 1; off < 256; off <<= 1) {
        int t = (tid >= off) ? ps[tid - off] : 0;
        __syncthreads();
        ps[tid] += t;
        __syncthreads();
    }
    int excl = ps[tid] - s;
    #pragma unroll
    for (int j = 0; j < 2; ++j) {
        int i = tid * 2 + j;
        if (i < NB) {
            lbase[i] = excl; excl += a[j];
            h[i] = (a[j] > 0) ? atomicAdd(&gcur[i * CURPAD], a[j]) : 0;
        }
    }
    __syncthreads();

    // place phase: stage bucket-ordered in LDS (col/val read once, here)
    #pragma unroll
    for (int k = 0; k < BIN_TILE / 256; ++k) {
        if (pkreg[k] >= 0) {
            long e = e0 + tid + k * 256;
            int b  = pkreg[k] >> 21;
            int rl = (pkreg[k] >> 12) & (BROWS - 1);
            int rk = pkreg[k] & 4095;
            int slot = lbase[b] + rk;
            sbuf[slot] = make_int2((rl << 18) | col[e], __float_as_int(val[e]));
            sbk[slot]  = (unsigned short)b;
        }
    }
    __syncthreads();

    // write phase: consecutive slots of a bucket -> consecutive global addrs
    long rem = NUM_EDGES - e0;
    int nt = (rem < BIN_TILE) ? (int)rem : BIN_TILE;
    for (int i = tid; i < nt; i += 256) {
        int b = sbk[i];
        tmp[(long)b * CAP + h[b] + (i - lbase[b])] = sbuf[i];
    }
}

// scan step A: per-256-row block scan of degrees; local exclusive + totals
__global__ void scan_local(const int* __restrict__ rcnt,
                           int* __restrict__ row_ptr,
                           int* __restrict__ tot) {
    __shared__ int ps[256];
    int tid = threadIdx.x;
    int i = blockIdx.x * 256 + tid;
    int v = (i < N_NODES) ? rcnt[i] : 0;
    ps[tid] = v;
    __syncthreads();
    for (int off = 1; off < 256; off <<= 1) {
        int t = (tid >= off) ? ps[tid - off] : 0;
        __syncthreads();
        ps[tid] += t;
        __syncthreads();
    }
    if (i < N_NODES) row_ptr[i] = ps[tid] - v;
    if (tid == 255) tot[blockIdx.x] = ps[255];
}

// scan step B: exclusive scan of NSB=586 block totals -> sboff
__global__ void boff_scan2(const int* __restrict__ tot, int* __restrict__ sboff) {
    __shared__ int ps[1024];
    int tid = threadIdx.x;
    int v = (tid < NSB) ? tot[tid] : 0;
    ps[tid] = v;
    __syncthreads();
    for (int off = 1; off < 1024; off <<= 1) {
        int t = (tid >= off) ? ps[tid - off] : 0;
        __syncthreads();
        ps[tid] += t;
        __syncthreads();
    }
    if (tid < NSB) sboff[tid] = ps[tid] - v;
}

// scan step C: add block offsets; materialize row_ptr and scatter cursors
__global__ void fixup_kernel(int* __restrict__ row_ptr,
                             const int* __restrict__ sboff,
                             int* __restrict__ rcur) {
    int i = blockIdx.x * blockDim.x + threadIdx.x;
    if (i < N_NODES) {
        int rp = row_ptr[i] + sboff[i >> 8];
        row_ptr[i] = rp;
        rcur[i] = rp;
    }
    if (i == 0) row_ptr[N_NODES] = NUM_EDGES;
}

// ---------------------------------------------------------------------------
// R12 finalize: single tmp read, direct scatter via per-row cursors.
// NB*CHUNKS = 1172 blocks (4x R11's parallelism), no hist pass, no tmp
// re-read. Writes land in the bucket's ~110KB packed window (L2-resident;
// R9 showed unconfined spray is what's fatal, and its atomic returns over
// 9375 lines were benign).
// ---------------------------------------------------------------------------
__global__ void finalize_scatter(const int2* __restrict__ tmp,
                                 const int*  __restrict__ gcur,   // totals
                                 int*  __restrict__ rcur,
                                 int2* __restrict__ packed) {
    int b = blockIdx.x / CHUNKS;
    int c = blockIdx.x % CHUNKS;
    int n = gcur[b * CURPAD];
    int rlo = b << BROWS_SHIFT;
    long lo_t = (long)b * CAP;
    int per = (n + CHUNKS - 1) / CHUNKS;
    int lo = c * per;
    int hi = lo + per; if (hi > n) hi = n;
    for (int i = lo + threadIdx.x; i < hi; i += 256) {
        int2 p = tmp[lo_t + i];
        int r = rlo + (((unsigned)p.x) >> 18);
        int pos = atomicAdd(&rcur[r], 1);
        packed[pos] = make_int2(p.x & 0x3FFFF, p.y);
    }
}

// ---------------------------------------------------------------------------
// 32-edge half processor: 16 bpermute broadcasts, 8 independent dwordx2
// gathers (4 x-rows per instruction), 32 fmas into 4 accumulators.
// ---------------------------------------------------------------------------
__device__ __forceinline__ void proc_half(int2 pk, int g4, unsigned t8,
                                          const unsigned short* __restrict__ x,
                                          int ofs,
                                          float& a0, float& a1,
                                          float& a2, float& a3) {
    int c[8], w[8];
    #pragma unroll
    for (int q = 0; q < 8; ++q) {
        int a = ofs + (q << 4) + g4;
        c[q] = __builtin_amdgcn_ds_bpermute(a, pk.x);
        w[q] = __builtin_amdgcn_ds_bpermute(a, pk.y);
    }
    uint2 u[8];
    #pragma unroll
    for (int q = 0; q < 8; ++q)
        u[q] = *(const uint2*)((const char*)x + (((unsigned)c[q] << 7) + t8));
    #pragma unroll
    for (int q = 0; q < 8; ++q) {
        float v = __int_as_float(w[q]);
        a0 = fmaf(v, __uint_as_float(u[q].x << 16), a0);
        a1 = fmaf(v, __uint_as_float(u[q].x & 0xFFFF0000u), a1);
        a2 = fmaf(v, __uint_as_float(u[q].y << 16), a2);
        a3 = fmaf(v, __uint_as_float(u[q].y & 0xFFFF0000u), a3);
    }
}

// ---------------------------------------------------------------------------
// SpMM mid layer: y = bf16(spmm(x)). RPW=4 rows/wave, pk-prefetch pipelining.
// ---------------------------------------------------------------------------
__global__ void spmm_mid(const int*  __restrict__ row_ptr,
                         const int2* __restrict__ packed,
                         const unsigned short* __restrict__ x,
                         unsigned short*       __restrict__ y) {
    int gid  = blockIdx.x * blockDim.x + threadIdx.x;
    int wg   = gid >> 6;
    int lane = gid & 63;
    int r0   = wg * RPW;
    if (r0 >= N_NODES) return;

    int t  = lane & 15;
    int g4 = (lane >> 4) << 2;
    unsigned int t8 = (unsigned)t << 3;

    int rp = 0;
    if (lane <= RPW) rp = row_ptr[r0 + lane];
    int sE[RPW + 1];
    #pragma unroll
    for (int k = 0; k <= RPW; ++k) sE[k] = __builtin_amdgcn_readlane(rp, k);

    int2 pk = make_int2(0, 0);
    if (sE[0] + lane < sE[1]) pk = packed[sE[0] + lane];

    #pragma unroll
    for (int k = 0; k < RPW; ++k) {
        int sC = sE[k], eC = sE[k + 1];
        int m  = eC - sC;
        int2 pkC = pk;

        if (k + 1 < RPW) {
            pk = make_int2(0, 0);
            if (sE[k + 1] + lane < sE[k + 2]) pk = packed[sE[k + 1] + lane];
        }

        float a0 = 0.f, a1 = 0.f, a2 = 0.f, a3 = 0.f;
        proc_half(pkC, g4, t8, x, 0, a0, a1, a2, a3);
        if (m > 32) proc_half(pkC, g4, t8, x, 128, a0, a1, a2, a3);

        for (int base = sC + 64; base < eC; base += 64) {   // rare: deg > 64
            int2 p2 = make_int2(0, 0);
            if (base + lane < eC) p2 = packed[base + lane];
            int mm = eC - base;
            proc_half(p2, g4, t8, x, 0, a0, a1, a2, a3);
            if (mm > 32) proc_half(p2, g4, t8, x, 128, a0, a1, a2, a3);
        }

        a0 += __shfl_xor(a0, 16, 64);
        a1 += __shfl_xor(a1, 16, 64);
        a2 += __shfl_xor(a2, 16, 64);
        a3 += __shfl_xor(a3, 16, 64);
        a0 += __shfl_xor(a0, 32, 64);
        a1 += __shfl_xor(a1, 32, 64);
        a2 += __shfl_xor(a2, 32, 64);
        a3 += __shfl_xor(a3, 32, 64);

        if (lane < 16) {                       // t == lane here
            long o4 = ((long)(r0 + k) << 4) + t;
            ushort4 bv;
            bv.x = f2bf(a0); bv.y = f2bf(a1);
            bv.z = f2bf(a2); bv.w = f2bf(a3);
            ((ushort4*)y)[o4] = bv;
        }
    }
}

// ---------------------------------------------------------------------------
// SpMM last layer, fused epilogue: out = 0.25*(emb_fp32 + c1 + c2 + acc3)
// ---------------------------------------------------------------------------
__global__ void spmm_last(const int*  __restrict__ row_ptr,
                          const int2* __restrict__ packed,
                          const unsigned short* __restrict__ x,    // c2
                          const unsigned short* __restrict__ c1,
                          const float4* __restrict__ ue4,
                          const float4* __restrict__ ie4,
                          float4* __restrict__ out4) {
    int gid  = blockIdx.x * blockDim.x + threadIdx.x;
    int wg   = gid >> 6;
    int lane = gid & 63;
    int r0   = wg * RPW;
    if (r0 >= N_NODES) return;

    int t  = lane & 15;
    int g4 = (lane >> 4) << 2;
    unsigned int t8 = (unsigned)t << 3;

    int rp = 0;
    if (lane <= RPW) rp = row_ptr[r0 + lane];
    int sE[RPW + 1];
    #pragma unroll
    for (int k = 0; k <= RPW; ++k) sE[k] = __builtin_amdgcn_readlane(rp, k);

    int2 pk = make_int2(0, 0);
    if (sE[0] + lane < sE[1]) pk = packed[sE[0] + lane];

    #pragma unroll
    for (int k = 0; k < RPW; ++k) {
        int r  = r0 + k;
        int sC = sE[k], eC = sE[k + 1];
        int m  = eC - sC;
        int2 pkC = pk;

        // epilogue operands for this row: issue early, hide under gathers
        float4  e4 = make_float4(0.f, 0.f, 0.f, 0.f);
        ushort4 a4 = make_ushort4(0, 0, 0, 0);
        ushort4 b4 = make_ushort4(0, 0, 0, 0);
        if (lane < 16) {
            long ei = ((long)r << 4) + t;
            e4 = (r < NUM_USERS) ? ue4[ei] : ie4[ei - ((long)NUM_USERS << 4)];
            a4 = ((const ushort4*)c1)[ei];
            b4 = ((const ushort4*)x)[ei];
        }

        if (k + 1 < RPW) {
            pk = make_int2(0, 0);
            if (sE[k + 1] + lane < sE[k + 2]) pk = packed[sE[k + 1] + lane];
        }

        float a0 = 0.f, a1 = 0.f, a2 = 0.f, a3 = 0.f;
        proc_half(pkC, g4, t8, x, 0, a0, a1, a2, a3);
        if (m > 32) proc_half(pkC, g4, t8, x, 128, a0, a1, a2, a3);

        for (int base = sC + 64; base < eC; base += 64) {   // rare: deg > 64
            int2 p2 = make_int2(0, 0);
            if (base + lane < eC) p2 = packed[base + lane];
            int mm = eC - base;
            proc_half(p2, g4, t8, x, 0, a0, a1, a2, a3);
            if (mm > 32) proc_half(p2, g4, t8, x, 128, a0, a1, a2, a3);
        }

        a0 += __shfl_xor(a0, 16, 64);
        a1 += __shfl_xor(a1, 16, 64);
        a2 += __shfl_xor(a2, 16, 64);
        a3 += __shfl_xor(a3, 16, 64);
        a0 += __shfl_xor(a0, 32, 64);
        a1 += __shfl_xor(a1, 32, 64);
        a2 += __shfl_xor(a2, 32, 64);
        a3 += __shfl_xor(a3, 32, 64);

        if (lane < 16) {                       // t == lane here
            long o4 = ((long)r << 4) + t;
            float4 o;
            o.x = ((e4.x + bf2f(a4.x)) + (bf2f(b4.x) + a0)) * 0.25f;
            o.y = ((e4.y + bf2f(a4.y)) + (bf2f(b4.y) + a1)) * 0.25f;
            o.z = ((e4.z + bf2f(a4.z)) + (bf2f(b4.z) + a2)) * 0.25f;
            o.w = ((e4.w + bf2f(a4.w)) + (bf2f(b4.w) + a3)) * 0.25f;
            out4[o4] = o;
        }
    }
}

// ------------------- fallback (round-1 atomic path, fp32) -------------------
__global__ void init_fp32_kernel(const float4* __restrict__ ue,
                                 const float4* __restrict__ ie,
                                 float4* __restrict__ cur,
                                 float4* __restrict__ out) {
    int i = blockIdx.x * blockDim.x + threadIdx.x;
    if (i >= N_TOT4) return;
    float4 v = (i < N_USER4) ? ue[i] : ie[i - N_USER4];
    cur[i] = v;
    out[i] = v;
}

__global__ void edge_kernel(const int*   __restrict__ row,
                            const int*   __restrict__ col,
                            const float* __restrict__ val,
                            const float* __restrict__ x,
                            float*       __restrict__ y) {
    long gid = (long)blockIdx.x * blockDim.x + threadIdx.x;
    int e = (int)(gid >> 4);
    if (e >= NUM_EDGES) return;
    int d = ((int)gid & 15) * 4;
    int   r = row[e];
    int   c = col[e];
    float v = val[e];
    const float4 xv = *(const float4*)(x + (long)c * EMBED_DIM + d);
    float* yp = y + (long)r * EMBED_DIM + d;
    atomicAdd(yp + 0, v * xv.x);
    atomicAdd(yp + 1, v * xv.y);
    atomicAdd(yp + 2, v * xv.z);
    atomicAdd(yp + 3, v * xv.w);
}

__global__ void update_kernel(float4* __restrict__ out,
                              const float4* __restrict__ nxt) {
    int i = blockIdx.x * blockDim.x + threadIdx.x;
    if (i >= N_TOT4) return;
    float4 o = out[i], n = nxt[i];
    o.x += n.x; o.y += n.y; o.z += n.z; o.w += n.w;
    out[i] = o;
}

__global__ void final_kernel(float4* __restrict__ out,
                             const float4* __restrict__ nxt) {
    int i = blockIdx.x * blockDim.x + threadIdx.x;
    if (i >= N_TOT4) return;
    float4 o = out[i], n = nxt[i];
    out[i] = make_float4((o.x + n.x) * 0.25f, (o.y + n.y) * 0.25f,
                         (o.z + n.z) * 0.25f, (o.w + n.w) * 0.25f);
}

__global__ void zero_buf_kernel(float4* __restrict__ b) {
    int i = blockIdx.x * blockDim.x + threadIdx.x;
    if (i < N_TOT4) b[i] = make_float4(0.f, 0.f, 0.f, 0.f);
}

extern "C" void kernel_launch(void* const* d_in, const int* in_sizes, int n_in,
                              void* d_out, int out_size, void* d_ws, size_t ws_size,
                              hipStream_t stream) {
    const float* user_emb  = (const float*)d_in[0];
    const float* item_emb  = (const float*)d_in[1];
    const float* edge_vals = (const float*)d_in[2];
    const int*   edge_row  = (const int*)  d_in[3];
    const int*   edge_col  = (const int*)  d_in[4];
    float* out = (float*)d_out;

    const int blk = 256;
    const int grid_nodes = (N_TOT4 + blk - 1) / blk;              // 9375
    const int grid_spmm  = (N_NODES / RPW * 64 + blk - 1) / blk;  // 9375

    const size_t BF     = (size_t)N_NODES * EMBED_DIM * sizeof(unsigned short); // 19.2 MB
    const size_t TMP    = (size_t)NB * CAP * sizeof(int2);    // 38.4 MB (hosts c1+c2 later)
    const size_t PACKED = (size_t)NUM_EDGES * sizeof(int2);   // 32 MB
    const size_t RP     = 600064;                             // (N_NODES+1)*4 padded
    // layout: bfA | tmp (c1,c2 alias) | packed | row_ptr | rcur | rcnt |
    //         gcur | tot | sboff
    const size_t need = BF + TMP + PACKED + 3 * RP + 32768;   // ~91.4 MB

    if (ws_size >= need) {
        unsigned short* bfA = (unsigned short*)d_ws;
        unsigned short* c1  = (unsigned short*)((char*)d_ws + BF);       // tmp[0 : 19.2M)
        unsigned short* c2  = (unsigned short*)((char*)d_ws + BF + BF);  // tmp[19.2M : 38.4M)
        int2* tmp     = (int2*)((char*)d_ws + BF);                       // dead after finalize
        int2* packed  = (int2*)((char*)d_ws + BF + TMP);
        int*  row_ptr = (int*) ((char*)d_ws + BF + TMP + PACKED);
        int*  rcur    = (int*) ((char*)d_ws + BF + TMP + PACKED + RP);
        int*  rcnt    = (int*) ((char*)d_ws + BF + TMP + PACKED + 2 * RP);
        int*  gcur    = (int*) ((char*)d_ws + BF + TMP + PACKED + 3 * RP);
        int*  tot     = gcur + NB * CURPAD;
        int*  sboff   = tot + 1024;

        init_kernel<<<grid_nodes, blk, 0, stream>>>(
            (const float4*)user_emb, (const float4*)item_emb, (ushort4*)bfA,
            gcur, rcnt);

        // --- build CSR: fused rank+place+rowcount -> row scan -> scatter ---
        bin_write_fused<<<NTILES, blk, 0, stream>>>(edge_row, edge_col,
                                                    edge_vals, gcur, rcnt, tmp);
        scan_local<<<NSB, blk, 0, stream>>>(rcnt, row_ptr, tot);
        boff_scan2<<<1, 1024, 0, stream>>>(tot, sboff);
        fixup_kernel<<<NSB, blk, 0, stream>>>(row_ptr, sboff, rcur);
        finalize_scatter<<<NB * CHUNKS, blk, 0, stream>>>(tmp, gcur, rcur,
                                                          packed);

        // --- 3 propagation layers; out touched only by the last one ---
        spmm_mid<<<grid_spmm, blk, 0, stream>>>(row_ptr, packed, bfA, c1);
        spmm_mid<<<grid_spmm, blk, 0, stream>>>(row_ptr, packed, c1, c2);
        spmm_last<<<grid_spmm, blk, 0, stream>>>(row_ptr, packed, c2, c1,
                                                 (const float4*)user_emb,
                                                 (const float4*)item_emb,
                                                 (float4*)out);
    } else {
        // fallback: round-1 atomic scatter path (fp32, needs 76.8 MB)
        const size_t BUF = (size_t)N_NODES * EMBED_DIM * sizeof(float);
        float* bufA = (float*)d_ws;
        float* bufB = (float*)((char*)d_ws + BUF);
        const long edge_threads = (long)NUM_EDGES * 16;
        const int grid_edges16 = (int)((edge_threads + blk - 1) / blk);

        init_fp32_kernel<<<grid_nodes, blk, 0, stream>>>(
            (const float4*)user_emb, (const float4*)item_emb,
            (float4*)bufA, (float4*)out);
        zero_buf_kernel<<<grid_nodes, blk, 0, stream>>>((float4*)bufB);

        edge_kernel<<<grid_edges16, blk, 0, stream>>>(edge_row, edge_col, edge_vals, bufA, bufB);
        update_kernel<<<grid_nodes, blk, 0, stream>>>((float4*)out, (const float4*)bufB);
        zero_buf_kernel<<<grid_nodes, blk, 0, stream>>>((float4*)bufA);

        edge_kernel<<<grid_edges16, blk, 0, stream>>>(edge_row, edge_col, edge_vals, bufB, bufA);
        update_kernel<<<grid_nodes, blk, 0, stream>>>((float4*)out, (const float4*)bufA);
        zero_buf_kernel<<<grid_nodes, blk, 0, stream>>>((float4*)bufB);

        edge_kernel<<<grid_edges16, blk, 0, stream>>>(edge_row, edge_col, edge_vals, bufA, bufB);
        final_kernel<<<grid_nodes, blk, 0, stream>>>((float4*)out, (const float4*)bufB);
    }
}

// Round 13
// 439.101 us; speedup vs baseline: 1.5187x; 1.5187x over previous
//
#include <hip/hip_runtime.h>

#define NUM_USERS 100000
#define NUM_ITEMS 50000
#define N_NODES   150000   // NUM_USERS + NUM_ITEMS
#define EMBED_DIM 64
#define NUM_EDGES 4000000

#define N_USER4  (NUM_USERS * EMBED_DIM / 4)   // 1,600,000
#define N_TOT4   (N_NODES  * EMBED_DIM / 4)    // 2,400,000

// bucket sort parameters: 293 buckets x 512 rows (R11: line-sized tmp runs)
#define BROWS_SHIFT 9
#define BROWS       (1 << BROWS_SHIFT)                    // 512
#define NB          ((N_NODES + BROWS - 1) / BROWS)       // 293
#define BIN_TILE    4096                                  // edges per tile
#define NTILES      ((NUM_EDGES + BIN_TILE - 1) / BIN_TILE)  // 977
#define CAP         16384  // tmp slots per bucket (mean 13653, sigma 117)

#define CURPAD 16          // ints per cursor: one 64B line each (R8 lesson)
#define RPW 4              // rows per wave in spmm

// bf16 helpers: store with round-to-nearest-even, load with shift (exact)
__device__ __forceinline__ unsigned short f2bf(float f) {
    unsigned int u = __float_as_uint(f);
    u = (u + 0x7fffu + ((u >> 16) & 1u)) >> 16;
    return (unsigned short)u;
}
__device__ __forceinline__ float bf2f(unsigned short b) {
    return __uint_as_float((unsigned int)b << 16);
}

// ---------------------------------------------------------------------------
// init: cur(bf16) = emb; zero the padded bucket cursor array.
// (R12's per-row rcnt REVERTED: 4M-scale global atomics cost ~150us on this
// chip regardless of fire-and-forget — measured R9 count ~130, R12 fused
// +131, R12 scatter ~208. LDS-tile ranking is the only cheap path.)
// ---------------------------------------------------------------------------
__global__ void init_kernel(const float4* __restrict__ ue,
                            const float4* __restrict__ ie,
                            ushort4* __restrict__ cur_bf,
                            int* __restrict__ gcur) {
    int i = blockIdx.x * blockDim.x + threadIdx.x;
    if (i < NB * CURPAD) gcur[i] = 0;
    if (i >= N_TOT4) return;
    float4 v = (i < N_USER4) ? ue[i] : ie[i - N_USER4];
    ushort4 b;
    b.x = f2bf(v.x); b.y = f2bf(v.y); b.z = f2bf(v.z); b.w = f2bf(v.w);
    cur_bf[i] = b;
}

// exclusive scan of NB=293 bucket totals (gcur[b*CURPAD]) -> boff
__global__ void boff_scan(const int* __restrict__ gcur, int* __restrict__ boff) {
    __shared__ int ps[1024];
    int tid = threadIdx.x;
    int v = (tid < NB) ? gcur[tid * CURPAD] : 0;
    ps[tid] = v;
    __syncthreads();
    for (int off = 1; off < 1024; off <<= 1) {
        int t = (tid >= off) ? ps[tid - off] : 0;
        __syncthreads();
        ps[tid] += t;
        __syncthreads();
    }
    if (tid < NB) boff[tid] = ps[tid] - v;
    if (tid == 0) boff[NB] = NUM_EDGES;
}

// ---------------------------------------------------------------------------
// Fused build pass 1 (R11, unchanged): rank + place per 4096-edge tile;
// per-tile bucket bases via one atomicAdd per active bucket on padded
// cursors (293 64B lines, ~977 ops/line — benign). NB=293 -> ~14-entry
// (112B) tmp runs, near-line-sized writes.
// tmp entry packs (rl<<18 | col, val): col<2^18, rl<2^9 (bits 18..26).
// pkreg packs (b<<21 | rl<<12 | rk): b<2^9, rl<2^9, rk<2^12 -> positive.
// ---------------------------------------------------------------------------
__global__ void bin_write_fused(const int*   __restrict__ row,
                                const int*   __restrict__ col,
                                const float* __restrict__ val,
                                int*  __restrict__ gcur,   // NB padded cursors
                                int2* __restrict__ tmp) {
    __shared__ int2 sbuf[BIN_TILE];                 // 32 KB
    __shared__ unsigned short sbk[BIN_TILE];        // 8 KB
    __shared__ int h[NB];                           // counts, then global base
    __shared__ int lbase[NB];
    __shared__ int ps[256];
    int tid = threadIdx.x;
    long e0 = (long)blockIdx.x * BIN_TILE;

    for (int i = tid; i < NB; i += 256) h[i] = 0;
    __syncthreads();

    // rank phase
    int pkreg[BIN_TILE / 256];
    #pragma unroll
    for (int k = 0; k < BIN_TILE / 256; ++k) {
        long e = e0 + tid + k * 256;
        pkreg[k] = -1;
        if (e < NUM_EDGES) {
            int r  = row[e];
            int b  = r >> BROWS_SHIFT;
            int rl = r & (BROWS - 1);
            int rk = atomicAdd(&h[b], 1);
            pkreg[k] = (b << 21) | (rl << 12) | rk;
        }
    }
    __syncthreads();

    // exclusive scan of h[NB] -> lbase (2 bins/thread, 512 >= 293);
    // then claim this tile's global base per bucket: h[i] = old gcur
    int a[2]; int s = 0;
    #pragma unroll
    for (int j = 0; j < 2; ++j) {
        int i = tid * 2 + j;
        a[j] = (i < NB) ? h[i] : 0;
        s += a[j];
    }
    ps[tid] = s;
    __syncthreads();
    for (int off = 1; off < 256; off <<= 1) {
        int t = (tid >= off) ? ps[tid - off] : 0;
        __syncthreads();
        ps[tid] += t;
        __syncthreads();
    }
    int excl = ps[tid] - s;
    #pragma unroll
    for (int j = 0; j < 2; ++j) {
        int i = tid * 2 + j;
        if (i < NB) {
            lbase[i] = excl; excl += a[j];
            h[i] = (a[j] > 0) ? atomicAdd(&gcur[i * CURPAD], a[j]) : 0;
        }
    }
    __syncthreads();

    // place phase: stage bucket-ordered in LDS (col/val read once, here)
    #pragma unroll
    for (int k = 0; k < BIN_TILE / 256; ++k) {
        if (pkreg[k] >= 0) {
            long e = e0 + tid + k * 256;
            int b  = pkreg[k] >> 21;
            int rl = (pkreg[k] >> 12) & (BROWS - 1);
            int rk = pkreg[k] & 4095;
            int slot = lbase[b] + rk;
            sbuf[slot] = make_int2((rl << 18) | col[e], __float_as_int(val[e]));
            sbk[slot]  = (unsigned short)b;
        }
    }
    __syncthreads();

    // write phase: consecutive slots of a bucket -> consecutive global addrs
    long rem = NUM_EDGES - e0;
    int nt = (rem < BIN_TILE) ? (int)rem : BIN_TILE;
    for (int i = tid; i < nt; i += 256) {
        int b = sbk[i];
        tmp[(long)b * CAP + h[b] + (i - lbase[b])] = sbuf[i];
    }
}

// ---------------------------------------------------------------------------
// Pass 2: per-bucket finalize. R13: 1024 threads/block (was 256). R11's 125us
// came from occupancy starvation: 293 blocks x 4 waves = 4 waves/CU running
// 2x54 latency-chained iterations. 1024 threads -> 16 waves/CU, 2x14 iters.
// Two-pass (hist, then scatter into the bucket's ~110KB L2-resident packed
// window); scan section runs on threads 0..255.
// ---------------------------------------------------------------------------
__global__ void finalize_bucket(const int2* __restrict__ tmp,
                                const int*  __restrict__ gcur,   // totals
                                const int*  __restrict__ boff,
                                int*  __restrict__ row_ptr,
                                int2* __restrict__ packed) {
    __shared__ int cnt_[BROWS];     // 512 row counters / cursors
    __shared__ int ps[256];
    int tid = threadIdx.x;
    int b   = blockIdx.x;
    long lo_t = (long)b * CAP;
    int n    = gcur[b * CURPAD];
    int base = boff[b];
    int rlo  = b << BROWS_SHIFT;

    if (tid < BROWS) cnt_[tid] = 0;
    __syncthreads();

    // pass 1: histogram of 512 row-slots (coalesced tmp read, 1024-wide)
    for (int i = tid; i < n; i += 1024)
        atomicAdd(&cnt_[((unsigned)tmp[lo_t + i].x) >> 18], 1);
    __syncthreads();

    // chunked exclusive scan of 512 bins via threads 0..255
    int v0 = 0, v1 = 0, s = 0;
    if (tid < 256) {
        v0 = cnt_[2 * tid]; v1 = cnt_[2 * tid + 1];
        s = v0 + v1;
        ps[tid] = s;
    }
    __syncthreads();
    for (int off = 1; off < 256; off <<= 1) {
        int t = (tid >= off && tid < 256) ? ps[tid - off] : 0;
        __syncthreads();
        if (tid < 256) ps[tid] += t;
        __syncthreads();
    }
    if (tid < 256) {
        int excl = ps[tid] - s;
        int r0 = rlo + 2 * tid;
        if (r0 < N_NODES)     row_ptr[r0]     = base + excl;
        if (r0 + 1 < N_NODES) row_ptr[r0 + 1] = base + excl + v0;
        cnt_[2 * tid]     = base + excl;       // global cursors
        cnt_[2 * tid + 1] = base + excl + v0;
    }
    if (b == NB - 1 && tid == 0) row_ptr[N_NODES] = NUM_EDGES;
    __syncthreads();

    // pass 2: scatter into final packed positions (L2-resident window)
    for (int i = tid; i < n; i += 1024) {
        int2 p = tmp[lo_t + i];
        int rl = ((unsigned)p.x) >> 18;
        int pos = atomicAdd(&cnt_[rl], 1);
        packed[pos] = make_int2(p.x & 0x3FFFF, p.y);
    }
}

// ---------------------------------------------------------------------------
// 32-edge half processor: 16 bpermute broadcasts, 8 independent dwordx2
// gathers (4 x-rows per instruction), 32 fmas into 4 accumulators.
// ---------------------------------------------------------------------------
__device__ __forceinline__ void proc_half(int2 pk, int g4, unsigned t8,
                                          const unsigned short* __restrict__ x,
                                          int ofs,
                                          float& a0, float& a1,
                                          float& a2, float& a3) {
    int c[8], w[8];
    #pragma unroll
    for (int q = 0; q < 8; ++q) {
        int a = ofs + (q << 4) + g4;
        c[q] = __builtin_amdgcn_ds_bpermute(a, pk.x);
        w[q] = __builtin_amdgcn_ds_bpermute(a, pk.y);
    }
    uint2 u[8];
    #pragma unroll
    for (int q = 0; q < 8; ++q)
        u[q] = *(const uint2*)((const char*)x + (((unsigned)c[q] << 7) + t8));
    #pragma unroll
    for (int q = 0; q < 8; ++q) {
        float v = __int_as_float(w[q]);
        a0 = fmaf(v, __uint_as_float(u[q].x << 16), a0);
        a1 = fmaf(v, __uint_as_float(u[q].x & 0xFFFF0000u), a1);
        a2 = fmaf(v, __uint_as_float(u[q].y << 16), a2);
        a3 = fmaf(v, __uint_as_float(u[q].y & 0xFFFF0000u), a3);
    }
}

// ---------------------------------------------------------------------------
// SpMM mid layer: y = bf16(spmm(x)). RPW=4 rows/wave, pk-prefetch pipelining.
// ---------------------------------------------------------------------------
__global__ void spmm_mid(const int*  __restrict__ row_ptr,
                         const int2* __restrict__ packed,
                         const unsigned short* __restrict__ x,
                         unsigned short*       __restrict__ y) {
    int gid  = blockIdx.x * blockDim.x + threadIdx.x;
    int wg   = gid >> 6;
    int lane = gid & 63;
    int r0   = wg * RPW;
    if (r0 >= N_NODES) return;

    int t  = lane & 15;
    int g4 = (lane >> 4) << 2;
    unsigned int t8 = (unsigned)t << 3;

    int rp = 0;
    if (lane <= RPW) rp = row_ptr[r0 + lane];
    int sE[RPW + 1];
    #pragma unroll
    for (int k = 0; k <= RPW; ++k) sE[k] = __builtin_amdgcn_readlane(rp, k);

    int2 pk = make_int2(0, 0);
    if (sE[0] + lane < sE[1]) pk = packed[sE[0] + lane];

    #pragma unroll
    for (int k = 0; k < RPW; ++k) {
        int sC = sE[k], eC = sE[k + 1];
        int m  = eC - sC;
        int2 pkC = pk;

        if (k + 1 < RPW) {
            pk = make_int2(0, 0);
            if (sE[k + 1] + lane < sE[k + 2]) pk = packed[sE[k + 1] + lane];
        }

        float a0 = 0.f, a1 = 0.f, a2 = 0.f, a3 = 0.f;
        proc_half(pkC, g4, t8, x, 0, a0, a1, a2, a3);
        if (m > 32) proc_half(pkC, g4, t8, x, 128, a0, a1, a2, a3);

        for (int base = sC + 64; base < eC; base += 64) {   // rare: deg > 64
            int2 p2 = make_int2(0, 0);
            if (base + lane < eC) p2 = packed[base + lane];
            int mm = eC - base;
            proc_half(p2, g4, t8, x, 0, a0, a1, a2, a3);
            if (mm > 32) proc_half(p2, g4, t8, x, 128, a0, a1, a2, a3);
        }

        a0 += __shfl_xor(a0, 16, 64);
        a1 += __shfl_xor(a1, 16, 64);
        a2 += __shfl_xor(a2, 16, 64);
        a3 += __shfl_xor(a3, 16, 64);
        a0 += __shfl_xor(a0, 32, 64);
        a1 += __shfl_xor(a1, 32, 64);
        a2 += __shfl_xor(a2, 32, 64);
        a3 += __shfl_xor(a3, 32, 64);

        if (lane < 16) {                       // t == lane here
            long o4 = ((long)(r0 + k) << 4) + t;
            ushort4 bv;
            bv.x = f2bf(a0); bv.y = f2bf(a1);
            bv.z = f2bf(a2); bv.w = f2bf(a3);
            ((ushort4*)y)[o4] = bv;
        }
    }
}

// ---------------------------------------------------------------------------
// SpMM last layer, fused epilogue: out = 0.25*(emb_fp32 + c1 + c2 + acc3)
// ---------------------------------------------------------------------------
__global__ void spmm_last(const int*  __restrict__ row_ptr,
                          const int2* __restrict__ packed,
                          const unsigned short* __restrict__ x,    // c2
                          const unsigned short* __restrict__ c1,
                          const float4* __restrict__ ue4,
                          const float4* __restrict__ ie4,
                          float4* __restrict__ out4) {
    int gid  = blockIdx.x * blockDim.x + threadIdx.x;
    int wg   = gid >> 6;
    int lane = gid & 63;
    int r0   = wg * RPW;
    if (r0 >= N_NODES) return;

    int t  = lane & 15;
    int g4 = (lane >> 4) << 2;
    unsigned int t8 = (unsigned)t << 3;

    int rp = 0;
    if (lane <= RPW) rp = row_ptr[r0 + lane];
    int sE[RPW + 1];
    #pragma unroll
    for (int k = 0; k <= RPW; ++k) sE[k] = __builtin_amdgcn_readlane(rp, k);

    int2 pk = make_int2(0, 0);
    if (sE[0] + lane < sE[1]) pk = packed[sE[0] + lane];

    #pragma unroll
    for (int k = 0; k < RPW; ++k) {
        int r  = r0 + k;
        int sC = sE[k], eC = sE[k + 1];
        int m  = eC - sC;
        int2 pkC = pk;

        // epilogue operands for this row: issue early, hide under gathers
        float4  e4 = make_float4(0.f, 0.f, 0.f, 0.f);
        ushort4 a4 = make_ushort4(0, 0, 0, 0);
        ushort4 b4 = make_ushort4(0, 0, 0, 0);
        if (lane < 16) {
            long ei = ((long)r << 4) + t;
            e4 = (r < NUM_USERS) ? ue4[ei] : ie4[ei - ((long)NUM_USERS << 4)];
            a4 = ((const ushort4*)c1)[ei];
            b4 = ((const ushort4*)x)[ei];
        }

        if (k + 1 < RPW) {
            pk = make_int2(0, 0);
            if (sE[k + 1] + lane < sE[k + 2]) pk = packed[sE[k + 1] + lane];
        }

        float a0 = 0.f, a1 = 0.f, a2 = 0.f, a3 = 0.f;
        proc_half(pkC, g4, t8, x, 0, a0, a1, a2, a3);
        if (m > 32) proc_half(pkC, g4, t8, x, 128, a0, a1, a2, a3);

        for (int base = sC + 64; base < eC; base += 64) {   // rare: deg > 64
            int2 p2 = make_int2(0, 0);
            if (base + lane < eC) p2 = packed[base + lane];
            int mm = eC - base;
            proc_half(p2, g4, t8, x, 0, a0, a1, a2, a3);
            if (mm > 32) proc_half(p2, g4, t8, x, 128, a0, a1, a2, a3);
        }

        a0 += __shfl_xor(a0, 16, 64);
        a1 += __shfl_xor(a1, 16, 64);
        a2 += __shfl_xor(a2, 16, 64);
        a3 += __shfl_xor(a3, 16, 64);
        a0 += __shfl_xor(a0, 32, 64);
        a1 += __shfl_xor(a1, 32, 64);
        a2 += __shfl_xor(a2, 32, 64);
        a3 += __shfl_xor(a3, 32, 64);

        if (lane < 16) {                       // t == lane here
            long o4 = ((long)r << 4) + t;
            float4 o;
            o.x = ((e4.x + bf2f(a4.x)) + (bf2f(b4.x) + a0)) * 0.25f;
            o.y = ((e4.y + bf2f(a4.y)) + (bf2f(b4.y) + a1)) * 0.25f;
            o.z = ((e4.z + bf2f(a4.z)) + (bf2f(b4.z) + a2)) * 0.25f;
            o.w = ((e4.w + bf2f(a4.w)) + (bf2f(b4.w) + a3)) * 0.25f;
            out4[o4] = o;
        }
    }
}

// ------------------- fallback (round-1 atomic path, fp32) -------------------
__global__ void init_fp32_kernel(const float4* __restrict__ ue,
                                 const float4* __restrict__ ie,
                                 float4* __restrict__ cur,
                                 float4* __restrict__ out) {
    int i = blockIdx.x * blockDim.x + threadIdx.x;
    if (i >= N_TOT4) return;
    float4 v = (i < N_USER4) ? ue[i] : ie[i - N_USER4];
    cur[i] = v;
    out[i] = v;
}

__global__ void edge_kernel(const int*   __restrict__ row,
                            const int*   __restrict__ col,
                            const float* __restrict__ val,
                            const float* __restrict__ x,
                            float*       __restrict__ y) {
    long gid = (long)blockIdx.x * blockDim.x + threadIdx.x;
    int e = (int)(gid >> 4);
    if (e >= NUM_EDGES) return;
    int d = ((int)gid & 15) * 4;
    int   r = row[e];
    int   c = col[e];
    float v = val[e];
    const float4 xv = *(const float4*)(x + (long)c * EMBED_DIM + d);
    float* yp = y + (long)r * EMBED_DIM + d;
    atomicAdd(yp + 0, v * xv.x);
    atomicAdd(yp + 1, v * xv.y);
    atomicAdd(yp + 2, v * xv.z);
    atomicAdd(yp + 3, v * xv.w);
}

__global__ void update_kernel(float4* __restrict__ out,
                              const float4* __restrict__ nxt) {
    int i = blockIdx.x * blockDim.x + threadIdx.x;
    if (i >= N_TOT4) return;
    float4 o = out[i], n = nxt[i];
    o.x += n.x; o.y += n.y; o.z += n.z; o.w += n.w;
    out[i] = o;
}

__global__ void final_kernel(float4* __restrict__ out,
                             const float4* __restrict__ nxt) {
    int i = blockIdx.x * blockDim.x + threadIdx.x;
    if (i >= N_TOT4) return;
    float4 o = out[i], n = nxt[i];
    out[i] = make_float4((o.x + n.x) * 0.25f, (o.y + n.y) * 0.25f,
                         (o.z + n.z) * 0.25f, (o.w + n.w) * 0.25f);
}

__global__ void zero_buf_kernel(float4* __restrict__ b) {
    int i = blockIdx.x * blockDim.x + threadIdx.x;
    if (i < N_TOT4) b[i] = make_float4(0.f, 0.f, 0.f, 0.f);
}

extern "C" void kernel_launch(void* const* d_in, const int* in_sizes, int n_in,
                              void* d_out, int out_size, void* d_ws, size_t ws_size,
                              hipStream_t stream) {
    const float* user_emb  = (const float*)d_in[0];
    const float* item_emb  = (const float*)d_in[1];
    const float* edge_vals = (const float*)d_in[2];
    const int*   edge_row  = (const int*)  d_in[3];
    const int*   edge_col  = (const int*)  d_in[4];
    float* out = (float*)d_out;

    const int blk = 256;
    const int grid_nodes = (N_TOT4 + blk - 1) / blk;              // 9375
    const int grid_spmm  = (N_NODES / RPW * 64 + blk - 1) / blk;  // 9375

    const size_t BF     = (size_t)N_NODES * EMBED_DIM * sizeof(unsigned short); // 19.2 MB
    const size_t TMP    = (size_t)NB * CAP * sizeof(int2);    // 38.4 MB (hosts c1+c2 later)
    const size_t PACKED = (size_t)NUM_EDGES * sizeof(int2);   // 32 MB
    const size_t RP     = 600064;                             // (N_NODES+1)*4 padded
    const size_t GC     = (size_t)NB * CURPAD * sizeof(int);  // ~19 KB padded cursors
    // layout: bfA | tmp (c1,c2 alias) | packed | rp | gcur | boff
    const size_t need = BF + TMP + PACKED + RP + GC + 8192;   // ~90.3 MB

    if (ws_size >= need) {
        unsigned short* bfA = (unsigned short*)d_ws;
        unsigned short* c1  = (unsigned short*)((char*)d_ws + BF);       // tmp[0 : 19.2M)
        unsigned short* c2  = (unsigned short*)((char*)d_ws + BF + BF);  // tmp[19.2M : 38.4M)
        int2* tmp     = (int2*)((char*)d_ws + BF);                       // dead after finalize
        int2* packed  = (int2*)((char*)d_ws + BF + TMP);
        int*  row_ptr = (int*) ((char*)d_ws + BF + TMP + PACKED);
        int*  gcur    = (int*) ((char*)d_ws + BF + TMP + PACKED + RP);
        int*  boff    = (int*) ((char*)d_ws + BF + TMP + PACKED + RP + GC);

        init_kernel<<<grid_nodes, blk, 0, stream>>>(
            (const float4*)user_emb, (const float4*)item_emb, (ushort4*)bfA,
            gcur);

        // --- build CSR: fused rank+place -> scan -> finalize (1024-thread) ---
        bin_write_fused<<<NTILES, blk, 0, stream>>>(edge_row, edge_col,
                                                    edge_vals, gcur, tmp);
        boff_scan<<<1, 1024, 0, stream>>>(gcur, boff);
        finalize_bucket<<<NB, 1024, 0, stream>>>(tmp, gcur, boff, row_ptr,
                                                 packed);

        // --- 3 propagation layers; out touched only by the last one ---
        spmm_mid<<<grid_spmm, blk, 0, stream>>>(row_ptr, packed, bfA, c1);
        spmm_mid<<<grid_spmm, blk, 0, stream>>>(row_ptr, packed, c1, c2);
        spmm_last<<<grid_spmm, blk, 0, stream>>>(row_ptr, packed, c2, c1,
                                                 (const float4*)user_emb,
                                                 (const float4*)item_emb,
                                                 (float4*)out);
    } else {
        // fallback: round-1 atomic scatter path (fp32, needs 76.8 MB)
        const size_t BUF = (size_t)N_NODES * EMBED_DIM * sizeof(float);
        float* bufA = (float*)d_ws;
        float* bufB = (float*)((char*)d_ws + BUF);
        const long edge_threads = (long)NUM_EDGES * 16;
        const int grid_edges16 = (int)((edge_threads + blk - 1) / blk);

        init_fp32_kernel<<<grid_nodes, blk, 0, stream>>>(
            (const float4*)user_emb, (const float4*)item_emb,
            (float4*)bufA, (float4*)out);
        zero_buf_kernel<<<grid_nodes, blk, 0, stream>>>((float4*)bufB);

        edge_kernel<<<grid_edges16, blk, 0, stream>>>(edge_row, edge_col, edge_vals, bufA, bufB);
        update_kernel<<<grid_nodes, blk, 0, stream>>>((float4*)out, (const float4*)bufB);
        zero_buf_kernel<<<grid_nodes, blk, 0, stream>>>((float4*)bufA);

        edge_kernel<<<grid_edges16, blk, 0, stream>>>(edge_row, edge_col, edge_vals, bufB, bufA);
        update_kernel<<<grid_nodes, blk, 0, stream>>>((float4*)out, (const float4*)bufA);
        zero_buf_kernel<<<grid_nodes, blk, 0, stream>>>((float4*)bufB);

        edge_kernel<<<grid_edges16, blk, 0, stream>>>(edge_row, edge_col, edge_vals, bufA, bufB);
        final_kernel<<<grid_nodes, blk, 0, stream>>>((float4*)out, (const float4*)bufB);
    }
}